// Round 4
// baseline (387.050 us; speedup 1.0000x reference)
//
#include <hip/hip_runtime.h>

#define N_NODES 50000
#define N_EDGES 500000
#define DIM 128
#define KC 1024
#define CAP 64
#define EPSV 1e-8f
#define TM 256
#define TN 128
#define KS 32

// map float to order-preserving uint (for packed atomicMax argmax)
__device__ __forceinline__ unsigned ford(float f) {
    unsigned b = __float_as_uint(f);
    return (b & 0x80000000u) ? ~b : (b | 0x80000000u);
}

// ---------------- Stage 1a: bucket edges by dst (int atomics only) ----------------
__global__ void fill_buckets_k(const int* __restrict__ ei, int* __restrict__ bucket,
                               int* __restrict__ cursor) {
    int e = blockIdx.x * blockDim.x + threadIdx.x;
    if (e >= N_EDGES) return;
    int src = ei[e];
    int dst = ei[N_EDGES + e];
    int pos = atomicAdd(cursor + dst, 1);
    if (pos < CAP) bucket[dst * CAP + pos] = src;
}

// ---------------- Stage 1b+2: deterministic mean-aggregate + L2 normalize ----------
__global__ void agg_norm_k(const float* __restrict__ x, const int* __restrict__ bucket,
                           const int* __restrict__ cursor, float* __restrict__ h,
                           float* __restrict__ hn) {
    int lane = threadIdx.x & 63;
    int wv = threadIdx.x >> 6;
    int n = blockIdx.x * 4 + wv;  // grid 12500 * 4 waves = 50000 exactly

    int cnt = cursor[n];
    if (cnt > CAP) cnt = CAP;
    int v = (lane < cnt) ? bucket[n * CAP + lane] : 0x7fffffff;

    // bitonic sort ascending across 64 lanes -> deterministic sum order
#pragma unroll
    for (int k = 2; k <= 64; k <<= 1) {
#pragma unroll
        for (int j = k >> 1; j >= 1; j >>= 1) {
            int other = __shfl_xor(v, j);
            bool lower = ((lane & j) == 0);
            bool asc = ((lane & k) == 0);
            int mn = min(v, other), mx = max(v, other);
            v = (lower == asc) ? mn : mx;
        }
    }

    const float2* x2 = (const float2*)x;
    float ax = 0.f, ay = 0.f;
    for (int j = 0; j < cnt; ++j) {
        int s = __shfl(v, j);
        float2 t = x2[(size_t)s * 64 + lane];
        ax += t.x; ay += t.y;
    }
    float degf = (float)(cnt > 0 ? cnt : 1);
    float hx = ax / degf, hy = ay / degf;

    float ss = hx * hx + hy * hy;
#pragma unroll
    for (int o = 1; o < 64; o <<= 1) ss += __shfl_xor(ss, o);
    float denom = sqrtf(ss) + EPSV;

    ((float2*)h)[(size_t)n * 64 + lane] = make_float2(hx, hy);
    ((float2*)hn)[(size_t)n * 64 + lane] = make_float2(hx / denom, hy / denom);
}

// ---------------- Stage 3: tiled vector GEMM + fused argmax ----------------
// 256x128 tile, 256 threads, per-thread 16x8 (4 row-segments of 64 x 2 col-halves).
// A-fragment reads: 4 distinct addrs/wave (broadcast). B: exact 2x wrap, free.
// 6 ds_read_b128 per 128 FMA -> VALU-bound. T14 reg-prefetch hides global latency.
__global__ __launch_bounds__(256, 2) void sim_argmax4_k(const float* __restrict__ hn,
                                                        unsigned long long* __restrict__ keys) {
    __shared__ float Asb[KS][TM];   // k-major, 32 KB
    __shared__ float Bsb[KS][TN];   // k-major, 16 KB
    const int tid = threadIdx.x;
    const int tx = tid & 15, ty = tid >> 4;
    const int m0 = blockIdx.x * TM;
    const int n0 = blockIdx.y * TN;

    float acc[16][8];
#pragma unroll
    for (int i = 0; i < 16; ++i)
#pragma unroll
        for (int j = 0; j < 8; ++j) acc[i][j] = 0.f;

    // staging: A = 1 thread per row (32 floats), B = 2 threads per row (16 each)
    int agn = m0 + tid; if (agn >= N_NODES) agn = N_NODES - 1;  // clamp tail (dup)
    const float* aptr = hn + (size_t)agn * DIM;
    const int bc = tid >> 1, bk = (tid & 1) << 4;
    const float* bptr = hn + (size_t)(n0 + bc) * DIM + bk;

    float4 apre[8], bpre[4];
#pragma unroll
    for (int q = 0; q < 8; ++q) apre[q] = *(const float4*)(aptr + q * 4);
#pragma unroll
    for (int q = 0; q < 4; ++q) bpre[q] = *(const float4*)(bptr + q * 4);

    for (int kc = 0; kc < DIM; kc += KS) {
#pragma unroll
        for (int q = 0; q < 8; ++q) {
            Asb[q * 4 + 0][tid] = apre[q].x; Asb[q * 4 + 1][tid] = apre[q].y;
            Asb[q * 4 + 2][tid] = apre[q].z; Asb[q * 4 + 3][tid] = apre[q].w;
        }
#pragma unroll
        for (int q = 0; q < 4; ++q) {
            Bsb[bk + q * 4 + 0][bc] = bpre[q].x; Bsb[bk + q * 4 + 1][bc] = bpre[q].y;
            Bsb[bk + q * 4 + 2][bc] = bpre[q].z; Bsb[bk + q * 4 + 3][bc] = bpre[q].w;
        }
        __syncthreads();
        if (kc + KS < DIM) {  // prefetch next K-chunk into regs (hidden under compute)
#pragma unroll
            for (int q = 0; q < 8; ++q) apre[q] = *(const float4*)(aptr + kc + KS + q * 4);
#pragma unroll
            for (int q = 0; q < 4; ++q) bpre[q] = *(const float4*)(bptr + kc + KS + q * 4);
        }
#pragma unroll 4
        for (int kk = 0; kk < KS; ++kk) {
            float4 ar0 = *(const float4*)&Asb[kk][(ty << 2)];
            float4 ar1 = *(const float4*)&Asb[kk][64 + (ty << 2)];
            float4 ar2 = *(const float4*)&Asb[kk][128 + (ty << 2)];
            float4 ar3 = *(const float4*)&Asb[kk][192 + (ty << 2)];
            float4 br0 = *(const float4*)&Bsb[kk][(tx << 2)];
            float4 br1 = *(const float4*)&Bsb[kk][64 + (tx << 2)];
            float a_[16] = {ar0.x, ar0.y, ar0.z, ar0.w, ar1.x, ar1.y, ar1.z, ar1.w,
                            ar2.x, ar2.y, ar2.z, ar2.w, ar3.x, ar3.y, ar3.z, ar3.w};
            float b_[8] = {br0.x, br0.y, br0.z, br0.w, br1.x, br1.y, br1.z, br1.w};
#pragma unroll
            for (int i = 0; i < 16; ++i)
#pragma unroll
                for (int j = 0; j < 8; ++j)
                    acc[i][j] = fmaf(a_[i], b_[j], acc[i][j]);
        }
        __syncthreads();
    }

    // fused argmax. cols ascending in j for every thread -> strict > = first max.
#pragma unroll
    for (int i = 0; i < 16; ++i) {
        float best = acc[i][0];
        int bj = 0;
#pragma unroll
        for (int j = 1; j < 8; ++j)
            if (acc[i][j] > best) { best = acc[i][j]; bj = j; }
        int bidx = n0 + ((bj < 4) ? ((tx << 2) + bj) : (64 + (tx << 2) + bj - 4));
#pragma unroll
        for (int o = 1; o < 16; o <<= 1) {
            float os = __shfl_xor(best, o);
            int oi = __shfl_xor(bidx, o);
            if (os > best || (os == best && oi < bidx)) { best = os; bidx = oi; }
        }
        if (tx == 0) {
            int gn = m0 + (i >> 2) * 64 + (ty << 2) + (i & 3);
            if (gn < N_NODES) {
                unsigned long long key =
                    ((unsigned long long)ford(best) << 32) | (unsigned)(KC - 1 - bidx);
                atomicMax(keys + gn, key);
            }
        }
    }
}

// ---------------- Stage 3b: decode packed keys -> assign ----------------
__global__ void decode_k(const unsigned long long* __restrict__ keys,
                         int* __restrict__ assign) {
    int n = blockIdx.x * 256 + threadIdx.x;
    if (n >= N_NODES) return;
    assign[n] = (KC - 1) - (int)(unsigned)(keys[n] & 0xFFFFFFFFull);
}

// ---------------- Stage 4: cluster sums (float atomics OK: smooth path) ----------
__global__ void cluster_acc_k(const float* __restrict__ h, const int* __restrict__ assign,
                              float* __restrict__ xc, int* __restrict__ counts) {
    int i = blockIdx.x * blockDim.x + threadIdx.x;  // 50000*32 exactly
    int n = i >> 5, q = i & 31;
    int a = assign[n];
    float4 v = ((const float4*)h)[(size_t)n * 32 + q];
    float* d = xc + a * DIM + q * 4;
    atomicAdd(d + 0, v.x);
    atomicAdd(d + 1, v.y);
    atomicAdd(d + 2, v.z);
    atomicAdd(d + 3, v.w);
    if (q == 0) atomicAdd(counts + a, 1);
}

// ---------------- Stage 5: y = (xc/counts) @ W1.T + b1 ----------------
__global__ void y_gemm_k(const float* __restrict__ xc, const int* __restrict__ counts,
                         const float* __restrict__ W1, const float* __restrict__ b1,
                         float* __restrict__ y) {
    __shared__ float xr[DIM];
    int c = blockIdx.x, t = threadIdx.x;  // 1024 blocks x 128 threads
    int cnt = counts[c];
    float cntf = (float)(cnt > 0 ? cnt : 1);
    xr[t] = xc[c * DIM + t] / cntf;
    __syncthreads();

    const float4* w4 = (const float4*)(W1 + t * DIM);
    float a0 = 0.f, a1 = 0.f, a2 = 0.f, a3 = 0.f;
#pragma unroll
    for (int kk = 0; kk < 32; ++kk) {
        float4 w = w4[kk];
        a0 = fmaf(xr[4 * kk + 0], w.x, a0);
        a1 = fmaf(xr[4 * kk + 1], w.y, a1);
        a2 = fmaf(xr[4 * kk + 2], w.z, a2);
        a3 = fmaf(xr[4 * kk + 3], w.w, a3);
    }
    y[c * DIM + t] = (a0 + a1) + (a2 + a3) + b1[t];
}

// ---------------- Stage 6: out = y[assign] ----------------
__global__ void scatter_out_k(const float* __restrict__ y, const int* __restrict__ assign,
                              float* __restrict__ out) {
    int i = blockIdx.x * blockDim.x + threadIdx.x;  // 50000*32 exactly
    int n = i >> 5, q = i & 31;
    int a = assign[n];
    ((float4*)out)[(size_t)n * 32 + q] = ((const float4*)y)[a * 32 + q];
}

extern "C" void kernel_launch(void* const* d_in, const int* in_sizes, int n_in,
                              void* d_out, int out_size, void* d_ws, size_t ws_size,
                              hipStream_t stream) {
    const float* x  = (const float*)d_in[0];
    const int*   ei = (const int*)d_in[1];
    const float* W1 = (const float*)d_in[2];
    const float* b1 = (const float*)d_in[3];
    float* out = (float*)d_out;

    char* ws = (char*)d_ws;
    // layout (bytes):
    //   h      @ 0          : 50000*128*4 = 25,600,000
    //   bucket @ 25,600,000 : 50000*64*4  = 12,800,000   (keys reuses this after agg)
    //   cursor @ 38,400,000 : 50000*4     =    200,000
    //   counts @ 38,600,000 : 1024*4      =      4,096
    //   xc     @ 38,604,096 : 1024*128*4  =    524,288
    //   assign @ 39,128,384 : 50000*4     =    200,000
    //   y      @ 39,328,384 : 1024*128*4  =    524,288
    float* h      = (float*)(ws);
    int*   bucket = (int*)(ws + 25600000);
    int*   cursor = (int*)(ws + 38400000);
    int*   counts = (int*)(ws + 38600000);
    float* xc     = (float*)(ws + 38604096);
    int*   assign = (int*)(ws + 39128384);
    float* y      = (float*)(ws + 39328384);
    float* hn     = out;  // hn lives in d_out; fully overwritten by scatter_out_k
    unsigned long long* keys = (unsigned long long*)(ws + 25600000);  // reuse bucket

    hipMemsetAsync(ws + 38400000, 0, 728384, stream);  // cursor + counts + xc

    fill_buckets_k<<<(N_EDGES + 255) / 256, 256, 0, stream>>>(ei, bucket, cursor);
    agg_norm_k<<<N_NODES / 4, 256, 0, stream>>>(x, bucket, cursor, h, hn);
    hipMemsetAsync(ws + 25600000, 0, N_NODES * 8, stream);  // zero keys (bucket is dead)
    sim_argmax4_k<<<dim3((N_NODES + TM - 1) / TM, KC / TN), 256, 0, stream>>>(hn, keys);
    decode_k<<<(N_NODES + 255) / 256, 256, 0, stream>>>(keys, assign);
    cluster_acc_k<<<(N_NODES * 32) / 256, 256, 0, stream>>>(h, assign, xc, counts);
    y_gemm_k<<<KC, 128, 0, stream>>>(xc, counts, W1, b1, y);
    scatter_out_k<<<(N_NODES * 32) / 256, 256, 0, stream>>>(y, assign, out);
}

// Round 5
// 382.579 us; speedup vs baseline: 1.0117x; 1.0117x over previous
//
#include <hip/hip_runtime.h>

#define N_NODES 50000
#define N_EDGES 500000
#define DIM 128
#define KC 1024
#define CAP 64
#define EPSV 1e-8f
#define LO_SCALE 4096.0f
#define INV_LO_SCALE (1.0f / 4096.0f)

typedef _Float16 f16x8 __attribute__((ext_vector_type(8)));
typedef _Float16 f16x2 __attribute__((ext_vector_type(2)));
typedef float f32x4 __attribute__((ext_vector_type(4)));

// map float to order-preserving uint (for packed atomicMax argmax)
__device__ __forceinline__ unsigned ford(float f) {
    unsigned b = __float_as_uint(f);
    return (b & 0x80000000u) ? ~b : (b | 0x80000000u);
}

// ---------------- Stage 1a: bucket edges by dst (int atomics only) ----------------
__global__ void fill_buckets_k(const int* __restrict__ ei, int* __restrict__ bucket,
                               int* __restrict__ cursor) {
    int e = blockIdx.x * blockDim.x + threadIdx.x;
    if (e >= N_EDGES) return;
    int src = ei[e];
    int dst = ei[N_EDGES + e];
    int pos = atomicAdd(cursor + dst, 1);
    if (pos < CAP) bucket[dst * CAP + pos] = src;
}

// ---------------- Stage 1b+2: deterministic mean-aggregate + normalize + fp16 split
// one wave per node; bitonic sort -> bit-deterministic sum across replays.
// writes h (fp32, ws) and the split-fp16 planes Ahi/Alo (d_out): hn = hi + lo/4096.
__global__ void agg_norm_k(const float* __restrict__ x, const int* __restrict__ bucket,
                           const int* __restrict__ cursor, float* __restrict__ h,
                           _Float16* __restrict__ Ahi, _Float16* __restrict__ Alo) {
    int lane = threadIdx.x & 63;
    int wv = threadIdx.x >> 6;
    int n = blockIdx.x * 4 + wv;  // grid 12500 * 4 waves = 50000 exactly

    int cnt = cursor[n];
    if (cnt > CAP) cnt = CAP;
    int v = (lane < cnt) ? bucket[n * CAP + lane] : 0x7fffffff;

    // bitonic sort ascending across 64 lanes -> deterministic sum order
#pragma unroll
    for (int k = 2; k <= 64; k <<= 1) {
#pragma unroll
        for (int j = k >> 1; j >= 1; j >>= 1) {
            int other = __shfl_xor(v, j);
            bool lower = ((lane & j) == 0);
            bool asc = ((lane & k) == 0);
            int mn = min(v, other), mx = max(v, other);
            v = (lower == asc) ? mn : mx;
        }
    }

    const float2* x2 = (const float2*)x;
    float ax = 0.f, ay = 0.f;
    for (int j = 0; j < cnt; ++j) {
        int s = __shfl(v, j);
        float2 t = x2[(size_t)s * 64 + lane];
        ax += t.x; ay += t.y;
    }
    float degf = (float)(cnt > 0 ? cnt : 1);
    float hx = ax / degf, hy = ay / degf;

    float ss = hx * hx + hy * hy;
#pragma unroll
    for (int o = 1; o < 64; o <<= 1) ss += __shfl_xor(ss, o);
    float denom = sqrtf(ss) + EPSV;
    float hnx = hx / denom, hny = hy / denom;

    ((float2*)h)[(size_t)n * 64 + lane] = make_float2(hx, hy);

    // split hn into fp16 hi + fp16 lo (lo pre-scaled by 4096 to stay normal)
    _Float16 hix = (_Float16)hnx, hiy = (_Float16)hny;
    _Float16 lox = (_Float16)((hnx - (float)hix) * LO_SCALE);
    _Float16 loy = (_Float16)((hny - (float)hiy) * LO_SCALE);
    f16x2 ph; ph[0] = hix; ph[1] = hiy;
    f16x2 pl; pl[0] = lox; pl[1] = loy;
    *(f16x2*)(Ahi + (size_t)n * DIM + lane * 2) = ph;
    *(f16x2*)(Alo + (size_t)n * DIM + lane * 2) = pl;
}

// ---------------- Stage 3: MFMA fp16x3 sim GEMM + fused argmax ----------------
// LDS-free. Block = 4 waves; wave tile 64x32 (4 M-subtiles x 2 N-subtiles of 16x16).
// mfma_f32_16x16x32_f16 fragments loaded straight from global: lane holds
// row (lane&15), k = (lane>>4)*8 + j  -> 16B coalesced per lane.
// s = acc_hh + (acc_hl + acc_lh) / 4096  (error ~2^-24, fp32-class).
__global__ __launch_bounds__(256) void sim_mfma_k(const _Float16* __restrict__ Ahi,
                                                  const _Float16* __restrict__ Alo,
                                                  unsigned long long* __restrict__ keys) {
    const int lane = threadIdx.x & 63;
    const int wv = threadIdx.x >> 6;          // 0..3
    const int m0 = blockIdx.x * 64;
    const int n0 = blockIdx.y * 128 + wv * 32;
    const int r16 = lane & 15, kg = lane >> 4;
    const int koff = kg * 8;

    int arow[4];
#pragma unroll
    for (int mi = 0; mi < 4; ++mi) {
        int r = m0 + mi * 16 + r16;
        arow[mi] = (r < N_NODES) ? r : (N_NODES - 1);  // tail clamp (dup, write skipped)
    }

    f32x4 acc1[4][2], acc2[4][2];
#pragma unroll
    for (int mi = 0; mi < 4; ++mi)
#pragma unroll
        for (int ni = 0; ni < 2; ++ni) {
            acc1[mi][ni] = (f32x4){0.f, 0.f, 0.f, 0.f};
            acc2[mi][ni] = (f32x4){0.f, 0.f, 0.f, 0.f};
        }

#pragma unroll
    for (int kc = 0; kc < DIM; kc += 32) {
        f16x8 ah[4], al[4], bh[2], bl[2];
#pragma unroll
        for (int mi = 0; mi < 4; ++mi) {
            size_t off = (size_t)arow[mi] * DIM + kc + koff;
            ah[mi] = *(const f16x8*)(Ahi + off);
            al[mi] = *(const f16x8*)(Alo + off);
        }
#pragma unroll
        for (int ni = 0; ni < 2; ++ni) {
            size_t off = (size_t)(n0 + ni * 16 + r16) * DIM + kc + koff;
            bh[ni] = *(const f16x8*)(Ahi + off);
            bl[ni] = *(const f16x8*)(Alo + off);
        }
#pragma unroll
        for (int mi = 0; mi < 4; ++mi)
#pragma unroll
            for (int ni = 0; ni < 2; ++ni) {
                acc1[mi][ni] = __builtin_amdgcn_mfma_f32_16x16x32_f16(
                    ah[mi], bh[ni], acc1[mi][ni], 0, 0, 0);
                acc2[mi][ni] = __builtin_amdgcn_mfma_f32_16x16x32_f16(
                    ah[mi], bl[ni], acc2[mi][ni], 0, 0, 0);
                acc2[mi][ni] = __builtin_amdgcn_mfma_f32_16x16x32_f16(
                    al[mi], bh[ni], acc2[mi][ni], 0, 0, 0);
            }
    }

    // fused argmax. C/D layout: col = lane&15, row = kg*4 + reg  (m89-verified).
    // per lane: 2 cols (ni=0,1), ascending -> strict > keeps first max.
#pragma unroll
    for (int mi = 0; mi < 4; ++mi) {
#pragma unroll
        for (int r = 0; r < 4; ++r) {
            float s0 = acc1[mi][0][r] + acc2[mi][0][r] * INV_LO_SCALE;
            float s1 = acc1[mi][1][r] + acc2[mi][1][r] * INV_LO_SCALE;
            float best = s0;
            int bidx = n0 + r16;
            if (s1 > best) { best = s1; bidx = n0 + 16 + r16; }
#pragma unroll
            for (int o = 1; o < 16; o <<= 1) {   // reduce over the 16 cols (same kg)
                float os = __shfl_xor(best, o);
                int oi = __shfl_xor(bidx, o);
                if (os > best || (os == best && oi < bidx)) { best = os; bidx = oi; }
            }
            if (r16 == 0) {
                int gr = m0 + mi * 16 + kg * 4 + r;
                if (gr < N_NODES) {
                    unsigned long long key =
                        ((unsigned long long)ford(best) << 32) | (unsigned)(KC - 1 - bidx);
                    atomicMax(keys + gr, key);
                }
            }
        }
    }
}

// ---------------- Stage 3b: decode packed keys -> assign ----------------
__global__ void decode_k(const unsigned long long* __restrict__ keys,
                         int* __restrict__ assign) {
    int n = blockIdx.x * 256 + threadIdx.x;
    if (n >= N_NODES) return;
    assign[n] = (KC - 1) - (int)(unsigned)(keys[n] & 0xFFFFFFFFull);
}

// ---------------- Stage 4: cluster sums (float atomics OK: smooth path) ----------
__global__ void cluster_acc_k(const float* __restrict__ h, const int* __restrict__ assign,
                              float* __restrict__ xc, int* __restrict__ counts) {
    int i = blockIdx.x * blockDim.x + threadIdx.x;  // 50000*32 exactly
    int n = i >> 5, q = i & 31;
    int a = assign[n];
    float4 v = ((const float4*)h)[(size_t)n * 32 + q];
    float* d = xc + a * DIM + q * 4;
    atomicAdd(d + 0, v.x);
    atomicAdd(d + 1, v.y);
    atomicAdd(d + 2, v.z);
    atomicAdd(d + 3, v.w);
    if (q == 0) atomicAdd(counts + a, 1);
}

// ---------------- Stage 5: y = (xc/counts) @ W1.T + b1 ----------------
__global__ void y_gemm_k(const float* __restrict__ xc, const int* __restrict__ counts,
                         const float* __restrict__ W1, const float* __restrict__ b1,
                         float* __restrict__ y) {
    __shared__ float xr[DIM];
    int c = blockIdx.x, t = threadIdx.x;  // 1024 blocks x 128 threads
    int cnt = counts[c];
    float cntf = (float)(cnt > 0 ? cnt : 1);
    xr[t] = xc[c * DIM + t] / cntf;
    __syncthreads();

    const float4* w4 = (const float4*)(W1 + t * DIM);
    float a0 = 0.f, a1 = 0.f, a2 = 0.f, a3 = 0.f;
#pragma unroll
    for (int kk = 0; kk < 32; ++kk) {
        float4 w = w4[kk];
        a0 = fmaf(xr[4 * kk + 0], w.x, a0);
        a1 = fmaf(xr[4 * kk + 1], w.y, a1);
        a2 = fmaf(xr[4 * kk + 2], w.z, a2);
        a3 = fmaf(xr[4 * kk + 3], w.w, a3);
    }
    y[c * DIM + t] = (a0 + a1) + (a2 + a3) + b1[t];
}

// ---------------- Stage 6: out = y[assign] ----------------
__global__ void scatter_out_k(const float* __restrict__ y, const int* __restrict__ assign,
                              float* __restrict__ out) {
    int i = blockIdx.x * blockDim.x + threadIdx.x;  // 50000*32 exactly
    int n = i >> 5, q = i & 31;
    int a = assign[n];
    ((float4*)out)[(size_t)n * 32 + q] = ((const float4*)y)[a * 32 + q];
}

extern "C" void kernel_launch(void* const* d_in, const int* in_sizes, int n_in,
                              void* d_out, int out_size, void* d_ws, size_t ws_size,
                              hipStream_t stream) {
    const float* x  = (const float*)d_in[0];
    const int*   ei = (const int*)d_in[1];
    const float* W1 = (const float*)d_in[2];
    const float* b1 = (const float*)d_in[3];
    float* out = (float*)d_out;

    char* ws = (char*)d_ws;
    // ws layout (bytes):
    //   h      @ 0          : 50000*128*4 = 25,600,000
    //   bucket @ 25,600,000 : 50000*64*4  = 12,800,000   (keys reuses this after agg)
    //   cursor @ 38,400,000 : 50000*4     =    200,000
    //   counts @ 38,600,000 : 1024*4      =      4,096
    //   xc     @ 38,604,096 : 1024*128*4  =    524,288
    //   assign @ 39,128,384 : 50000*4     =    200,000
    //   y      @ 39,328,384 : 1024*128*4  =    524,288
    float* h      = (float*)(ws);
    int*   bucket = (int*)(ws + 25600000);
    int*   cursor = (int*)(ws + 38400000);
    int*   counts = (int*)(ws + 38600000);
    float* xc     = (float*)(ws + 38604096);
    int*   assign = (int*)(ws + 39128384);
    float* y      = (float*)(ws + 39328384);
    unsigned long long* keys = (unsigned long long*)(ws + 25600000);  // reuse bucket

    // d_out (25.6 MB) temporarily holds the split fp16 planes of hn:
    //   Ahi @ 0 (12.8 MB), Alo @ 12.8 MB. Fully overwritten by scatter_out_k.
    _Float16* Ahi = (_Float16*)d_out;
    _Float16* Alo = (_Float16*)((char*)d_out + 12800000);

    hipMemsetAsync(ws + 38400000, 0, 728384, stream);  // cursor + counts + xc

    fill_buckets_k<<<(N_EDGES + 255) / 256, 256, 0, stream>>>(ei, bucket, cursor);
    agg_norm_k<<<N_NODES / 4, 256, 0, stream>>>(x, bucket, cursor, h, Ahi, Alo);
    hipMemsetAsync(ws + 25600000, 0, N_NODES * 8, stream);  // zero keys (bucket dead)
    sim_mfma_k<<<dim3((N_NODES + 63) / 64, KC / 128), 256, 0, stream>>>(Ahi, Alo, keys);
    decode_k<<<(N_NODES + 255) / 256, 256, 0, stream>>>(keys, assign);
    cluster_acc_k<<<(N_NODES * 32) / 256, 256, 0, stream>>>(h, assign, xc, counts);
    y_gemm_k<<<KC, 128, 0, stream>>>(xc, counts, W1, b1, y);
    scatter_out_k<<<(N_NODES * 32) / 256, 256, 0, stream>>>(y, assign, out);
}